// Round 3
// baseline (68.271 us; speedup 1.0000x reference)
//
#include <hip/hip_runtime.h>

// Block-per-4-rays, sort-free composite, payload-deferred, color-prefetch.
// Phase 1: each thread owns 4 consecutive voxels (float4 loads, amortized
//   across 4 rays) and slab-tests them against the block's 4 rays (16 tests).
//   Hit body is tiny: pack 64-bit key (ordered-uint tn | voxel id), shared
//   atomicAdd slot into the per-ray compaction arrays, store {key, tn, tf}.
// Phase 2: wave r composites ray r (all 4 waves busy, no idle waves).
//   Pass A (lane l owns hits l, l+64): sigma/alpha/ws/dep; ws -> LDS
//     (same-wave RAW, program-order within the wave); PREFETCH the 27 color
//     floats so their global latency hides under pass B's m-loop.
//   Pass B: T_before(l) = prod over {j : key_j < key_l} of (1-ws_j)
//     (predicate product over broadcast LDS reads — no sort, no scan),
//     proc mask, SH color + sigmoid, butterfly reduce 5 sums, write.
// 2 barriers, ~10.3 KB LDS.
// (R2 bench was an infra failure — "container failed twice" — source
//  re-audited: no OOB, LDS slot-guarded, no capture hazards. Resubmitting.)

#define BLOCK 256
#define RPB   4
#define CAP   128
#define EARLY_STOP 0.01f

__global__ __launch_bounds__(BLOCK) void voxel_raster(
    const float* __restrict__ positions, const float* __restrict__ sizes,
    const float* __restrict__ densities, const float* __restrict__ colors,
    const float* __restrict__ ray_o, const float* __restrict__ ray_d,
    float* __restrict__ out, int B)
{
    const int tid   = threadIdx.x;
    const int lane  = tid & 63;
    const int wv    = tid >> 6;            // 0..3
    const int rbase = blockIdx.x * RPB;

    __shared__ int cnt[RPB];
    __shared__ unsigned long long key[RPB][CAP];
    __shared__ float h_tn[RPB][CAP], h_tf[RPB][CAP], h_ws[RPB][CAP];

    if (tid < RPB) cnt[tid] = 0;
    __syncthreads();

    // ---- phase 1: 4 voxels/thread x 4 rays, AABB + compaction only ----
    const float4 P0 = ((const float4*)positions)[tid*3+0];
    const float4 P1 = ((const float4*)positions)[tid*3+1];
    const float4 P2 = ((const float4*)positions)[tid*3+2];
    const float4 SZ = ((const float4*)sizes)[tid];

    const float pxa[4] = {P0.x, P0.w, P1.z, P2.y};
    const float pya[4] = {P0.y, P1.x, P1.w, P2.z};
    const float pza[4] = {P0.z, P1.y, P2.x, P2.w};
    const float hsa[4] = {SZ.x*0.5f, SZ.y*0.5f, SZ.z*0.5f, SZ.w*0.5f};

    // block-uniform ray params (unrolled constant indexing -> registers)
    float rox[RPB], roy[RPB], roz[RPB], rix[RPB], riy[RPB], riz[RPB];
    #pragma unroll
    for (int r = 0; r < RPB; ++r) {
        const int b = (rbase + r < B) ? (rbase + r) : 0;
        rox[r] = ray_o[b*3+0]; roy[r] = ray_o[b*3+1]; roz[r] = ray_o[b*3+2];
        rix[r] = 1.0f / ray_d[b*3+0];
        riy[r] = 1.0f / ray_d[b*3+1];
        riz[r] = 1.0f / ray_d[b*3+2];
    }

    #pragma unroll
    for (int k = 0; k < 4; ++k) {
        const int n = tid*4 + k;
        const float lox = pxa[k]-hsa[k], hix = pxa[k]+hsa[k];
        const float loy = pya[k]-hsa[k], hiy = pya[k]+hsa[k];
        const float loz = pza[k]-hsa[k], hiz = pza[k]+hsa[k];
        #pragma unroll
        for (int r = 0; r < RPB; ++r) {
            float a0 = (lox - rox[r]) * rix[r], a1 = (hix - rox[r]) * rix[r];
            float tn = fminf(a0, a1), tf = fmaxf(a0, a1);
            a0 = (loy - roy[r]) * riy[r]; a1 = (hiy - roy[r]) * riy[r];
            tn = fmaxf(tn, fminf(a0, a1)); tf = fminf(tf, fmaxf(a0, a1));
            a0 = (loz - roz[r]) * riz[r]; a1 = (hiz - roz[r]) * riz[r];
            tn = fmaxf(tn, fminf(a0, a1)); tf = fminf(tf, fmaxf(a0, a1));
            if ((tf > tn) && (tf > 0.0f)) {
                const int slot = atomicAdd(&cnt[r], 1);
                if (slot < CAP) {
                    unsigned u = __float_as_uint(tn);
                    u = (u & 0x80000000u) ? ~u : (u | 0x80000000u);
                    key[r][slot]  = ((unsigned long long)u << 32) | (unsigned)n;
                    h_tn[r][slot] = tn;
                    h_tf[r][slot] = tf;
                }
            }
        }
    }
    __syncthreads();

    // ---- phase 2: wave wv composites ray rbase+wv (dense lanes) ----
    const int b = rbase + wv;
    if (b < B) {
        // per-wave ray dir reload (avoids runtime-indexed register arrays)
        const float dx = ray_d[b*3+0], dy = ray_d[b*3+1], dz = ray_d[b*3+2];
        float sh[9];
        sh[0]=1.0f; sh[1]=dy; sh[2]=dz; sh[3]=dx;
        sh[4]=dx*dy; sh[5]=dy*dz; sh[6]=3.0f*dz*dz-1.0f; sh[7]=dx*dz; sh[8]=dx*dx-dy*dy;

        const int total = cnt[wv];
        const int m = (total < CAP) ? total : CAP;

        // pass A: per-hit weights; lane l owns hits l and l+64
        float ws0 = 0.f, dep0 = 0.f, col0[27];
        if (lane < m) {
            const int n    = (int)(unsigned)key[wv][lane];
            const float tn = h_tn[wv][lane], tf = h_tf[wv][lane];
            const float sigma = __expf(densities[n]);
            const float dt    = tf - tn;
            const float alpha = 1.0f - __expf(-sigma * dt * 0.125f);
            const float base  = 1.0f - alpha + 1e-8f;
            float pw = 1.0f, ws = 0.f, dep = 0.f;
            #pragma unroll
            for (int i = 0; i < 8; ++i) {
                const float w = alpha * pw;
                ws  += w;
                dep += w * (tn + dt * ((float)i * (1.0f / 7.0f)));
                pw  *= base;
            }
            h_ws[wv][lane] = ws;       // same-wave readers; program order
            ws0 = ws; dep0 = dep;
            #pragma unroll
            for (int c = 0; c < 27; ++c)           // prefetch: latency hides
                col0[c] = colors[n*27 + c];        // under pass B's m-loop
        }
        int nn1 = 0; float ws1 = 0.f, dep1 = 0.f;
        if (lane + 64 < m) {                        // rare (m > 64)
            const int l    = lane + 64;
            const int n    = (int)(unsigned)key[wv][l];
            const float tn = h_tn[wv][l], tf = h_tf[wv][l];
            const float sigma = __expf(densities[n]);
            const float dt    = tf - tn;
            const float alpha = 1.0f - __expf(-sigma * dt * 0.125f);
            const float base  = 1.0f - alpha + 1e-8f;
            float pw = 1.0f, ws = 0.f, dep = 0.f;
            #pragma unroll
            for (int i = 0; i < 8; ++i) {
                const float w = alpha * pw;
                ws  += w;
                dep += w * (tn + dt * ((float)i * (1.0f / 7.0f)));
                pw  *= base;
            }
            h_ws[wv][l] = ws;
            nn1 = n; ws1 = ws; dep1 = dep;
        }

        // pass B: predicate-product composite
        float ra = 0.f, ga = 0.f, ba = 0.f, da = 0.f, wa = 0.f;
        if (lane < m) {
            const unsigned long long kl = key[wv][lane];
            float Tb = 1.0f;
            for (int j = 0; j < m; ++j) {           // broadcast LDS reads
                const unsigned long long kj = key[wv][j];
                const float wj = h_ws[wv][j];
                Tb *= (kj < kl) ? (1.0f - wj) : 1.0f;
            }
            if (Tb >= EARLY_STOP) {
                const float c = Tb * ws0;
                float ar = 0.f, ag = 0.f, ab = 0.f;
                #pragma unroll
                for (int cc = 0; cc < 9; ++cc) {
                    ar += sh[cc] * col0[cc];
                    ag += sh[cc] * col0[9 + cc];
                    ab += sh[cc] * col0[18 + cc];
                }
                ra += c * __fdividef(1.0f, 1.0f + __expf(-ar));
                ga += c * __fdividef(1.0f, 1.0f + __expf(-ag));
                ba += c * __fdividef(1.0f, 1.0f + __expf(-ab));
                da += Tb * dep0;
                wa += c;
            }
        }
        if (lane + 64 < m) {                        // rare tail, inline loads
            const int l = lane + 64;
            const unsigned long long kl = key[wv][l];
            float Tb = 1.0f;
            for (int j = 0; j < m; ++j) {
                const unsigned long long kj = key[wv][j];
                const float wj = h_ws[wv][j];
                Tb *= (kj < kl) ? (1.0f - wj) : 1.0f;
            }
            if (Tb >= EARLY_STOP) {
                const float c = Tb * ws1;
                float ar = 0.f, ag = 0.f, ab = 0.f;
                #pragma unroll
                for (int cc = 0; cc < 9; ++cc) {
                    ar += sh[cc] * colors[nn1*27 + cc];
                    ag += sh[cc] * colors[nn1*27 + 9 + cc];
                    ab += sh[cc] * colors[nn1*27 + 18 + cc];
                }
                ra += c * __fdividef(1.0f, 1.0f + __expf(-ar));
                ga += c * __fdividef(1.0f, 1.0f + __expf(-ag));
                ba += c * __fdividef(1.0f, 1.0f + __expf(-ab));
                da += Tb * dep1;
                wa += c;
            }
        }

        // butterfly reduce the 5 sums across the wave
        #pragma unroll
        for (int off = 32; off > 0; off >>= 1) {
            ra += __shfl_down(ra, off, 64);
            ga += __shfl_down(ga, off, 64);
            ba += __shfl_down(ba, off, 64);
            da += __shfl_down(da, off, 64);
            wa += __shfl_down(wa, off, 64);
        }
        if (lane == 0) {
            out[b*3+0] = ra;
            out[b*3+1] = ga;
            out[b*3+2] = ba;
            out[B*3+b] = (total > 0) ? da : 100.0f;   // FAR_PLANE if no hit
            out[B*4+b] = wa;
        }
    }
}

extern "C" void kernel_launch(void* const* d_in, const int* in_sizes, int n_in,
                              void* d_out, int out_size, void* d_ws, size_t ws_size,
                              hipStream_t stream) {
    const float* positions = (const float*)d_in[0];
    const float* sizes     = (const float*)d_in[1];
    const float* densities = (const float*)d_in[2];
    const float* colors    = (const float*)d_in[3];
    const float* ray_o     = (const float*)d_in[4];
    const float* ray_d     = (const float*)d_in[5];
    const int B = in_sizes[4] / 3;      // 2048 rays (N fixed at 1024)

    voxel_raster<<<(B + RPB - 1) / RPB, BLOCK, 0, stream>>>(
        positions, sizes, densities, colors, ray_o, ray_d, (float*)d_out, B);
}